// Round 9
// baseline (634.997 us; speedup 1.0000x reference)
//
#include <hip/hip_runtime.h>
#include <hip/hip_cooperative_groups.h>
#include <hip/hip_bf16.h>
#include <math.h>

namespace cg = cooperative_groups;

#define N_TOK 1024
#define N_ATOM 24576
#define C_S 384
#define NH 4
#define HD 96

typedef __attribute__((ext_vector_type(8))) short short8;   // 8 bf16
typedef __attribute__((ext_vector_type(4))) float f32x4;

// ---- workspace layout (float-slot offsets) ----
#define OFF_SEGX   0u
#define OFF_NOISE  4096u
#define OFF_NSPROJ 4352u
#define OFF_TF1    4736u
#define OFF_TF2    397952u
#define OFF_TF3    791168u
#define OFF_QKV    1184384u
#define OFF_AOB    1774208u
#define OFF_LNHB   1970816u
#define OFF_H1B    2167424u
#define OFF_WINB   2953856u
#define OFF_WOUTB  3175040u
#define OFF_WF1B   3248768u
#define OFF_WF2B   3543680u
#define OFF_TF1B   3838592u

__device__ inline __hip_bfloat16 f2bf(float x) { return __float2bfloat16(x); }
union BFPack { short8 v; __hip_bfloat16 h[8]; };
__device__ inline short8 pack8(float4 a, float4 b)
{
    BFPack p;
    p.h[0] = f2bf(a.x); p.h[1] = f2bf(a.y); p.h[2] = f2bf(a.z); p.h[3] = f2bf(a.w);
    p.h[4] = f2bf(b.x); p.h[5] = f2bf(b.y); p.h[6] = f2bf(b.z); p.h[7] = f2bf(b.w);
    return p.v;
}

// ---- shared memory union: max branch = attn = 32768 B exactly ----
union SMem {
    struct { __hip_bfloat16 As[64][72]; __hip_bfloat16 Bs[64][72]; } g;   // 18432 B
    struct {
        __hip_bfloat16 Ks[64][104];   // 13312
        __hip_bfloat16 Vt[96][72];    // 13824
        __hip_bfloat16 Ps[32][72];    //  4608
        float wmax[32][4];            //   512
        float wsum[32][4];            //   512
    } a;
    float red[4];
};

// ---------------------------------------------------------------------------
// R5-proven 64x64 bf16 MFMA GEMM tile (4 waves x 32x32), runs on one block.
template <int ACT, bool RES, bool OB>
__device__ __forceinline__ void gemm_tile(
    SMem& smem, const __hip_bfloat16* __restrict__ A,
    const __hip_bfloat16* __restrict__ W,
    const float* __restrict__ bias, const float* __restrict__ res,
    float* __restrict__ Cf, __hip_bfloat16* __restrict__ Cb,
    int N, int K, int bm, int bn, int tid)
{
    auto& As = smem.g.As;
    auto& Bs = smem.g.Bs;
    int w = tid >> 6, lane = tid & 63;
    int wr = (w >> 1) * 32, wc = (w & 1) * 32;
    int fr = lane & 15, kg = lane >> 4;
    int sr = tid >> 2, sc = (tid & 3) << 4;

    f32x4 acc[2][2] = {};
    for (int k0 = 0; k0 < K; k0 += 64) {
        const __hip_bfloat16* ag = A + (size_t)(bm + sr) * K + k0 + sc;
        const __hip_bfloat16* wg = W + (size_t)(bn + sr) * K + k0 + sc;
        short8 a0 = *(const short8*)(ag + 0);
        short8 a1 = *(const short8*)(ag + 8);
        short8 b0 = *(const short8*)(wg + 0);
        short8 b1 = *(const short8*)(wg + 8);
        __syncthreads();
        *(short8*)&As[sr][sc + 0] = a0;
        *(short8*)&As[sr][sc + 8] = a1;
        *(short8*)&Bs[sr][sc + 0] = b0;
        *(short8*)&Bs[sr][sc + 8] = b1;
        __syncthreads();

        short8 af[2][2], bf[2][2];
        #pragma unroll
        for (int i = 0; i < 2; ++i)
            #pragma unroll
            for (int kh = 0; kh < 2; ++kh) {
                af[i][kh] = *(const short8*)&As[wr + i * 16 + fr][kh * 32 + kg * 8];
                bf[i][kh] = *(const short8*)&Bs[wc + i * 16 + fr][kh * 32 + kg * 8];
            }
        #pragma unroll
        for (int kh = 0; kh < 2; ++kh)
            #pragma unroll
            for (int i = 0; i < 2; ++i)
                #pragma unroll
                for (int j = 0; j < 2; ++j)
                    acc[i][j] = __builtin_amdgcn_mfma_f32_16x16x32_bf16(
                        af[i][kh], bf[j][kh], acc[i][j], 0, 0, 0);
    }

    #pragma unroll
    for (int i = 0; i < 2; ++i)
        #pragma unroll
        for (int j = 0; j < 2; ++j) {
            int n = bn + wc + j * 16 + fr;
            float bv = bias[n];
            #pragma unroll
            for (int r = 0; r < 4; ++r) {
                int m = bm + wr + i * 16 + kg * 4 + r;
                float v = acc[i][j][r] + bv;
                if (ACT == 1) v = v / (1.f + __expf(-v));   // silu
                if (RES) v += res[(size_t)m * N + n];
                if (OB) Cb[(size_t)m * N + n] = f2bf(v);
                else    Cf[(size_t)m * N + n] = v;
            }
        }
}

// ---------------------------------------------------------------------------
// R5-proven MFMA flash attention tile: one block = (32 Q-rows, one head).
__device__ __forceinline__ void attn_tile(
    SMem& smem, const __hip_bfloat16* __restrict__ qkv,
    __hip_bfloat16* __restrict__ ao, int row0, int h, int tid)
{
    auto& Ks = smem.a.Ks;
    auto& Vt = smem.a.Vt;
    auto& Ps = smem.a.Ps;
    auto& wmax = smem.a.wmax;
    auto& wsum = smem.a.wsum;

    int w = tid >> 6, l = tid & 63;
    int fr = l & 15, kg = l >> 4;
    const float scale = 0.1020620726f;   // 1/sqrt(96)

    short8 qf[2][3];
    #pragma unroll
    for (int qs = 0; qs < 2; ++qs)
        #pragma unroll
        for (int dg = 0; dg < 3; ++dg)
            qf[qs][dg] = *(const short8*)(qkv
                + (size_t)(row0 + qs * 16 + fr) * 1152 + h * 96 + dg * 32 + kg * 8);

    float m[2][4], lsum[2][4];
    #pragma unroll
    for (int qs = 0; qs < 2; ++qs)
        #pragma unroll
        for (int r = 0; r < 4; ++r) { m[qs][r] = -1e30f; lsum[qs][r] = 0.f; }

    const int myqs = w >> 1;
    const int d0 = (w & 1) * 48;
    f32x4 acc_o[3] = {};

    int st_t = tid >> 2, st_c = (tid & 3) * 24;
    int vt_t = tid & 63, vt_d = (tid >> 6) * 24;

    for (int tile = 0; tile < N_TOK / 64; ++tile) {
        int t0 = tile * 64;
        __syncthreads();
        {
            const __hip_bfloat16* src =
                qkv + (size_t)(t0 + st_t) * 1152 + 384 + h * 96 + st_c;
            short8 k0 = *(const short8*)(src);
            short8 k1 = *(const short8*)(src + 8);
            short8 k2 = *(const short8*)(src + 16);
            *(short8*)&Ks[st_t][st_c + 0]  = k0;
            *(short8*)&Ks[st_t][st_c + 8]  = k1;
            *(short8*)&Ks[st_t][st_c + 16] = k2;
        }
        {
            const __hip_bfloat16* src =
                qkv + (size_t)(t0 + vt_t) * 1152 + 768 + h * 96 + vt_d;
            BFPack p0, p1, p2;
            p0.v = *(const short8*)(src);
            p1.v = *(const short8*)(src + 8);
            p2.v = *(const short8*)(src + 16);
            #pragma unroll
            for (int j = 0; j < 8; ++j) {
                Vt[vt_d + j][vt_t]      = p0.h[j];
                Vt[vt_d + 8 + j][vt_t]  = p1.h[j];
                Vt[vt_d + 16 + j][vt_t] = p2.h[j];
            }
        }
        __syncthreads();

        f32x4 s[2] = {};
        #pragma unroll
        for (int dg = 0; dg < 3; ++dg) {
            short8 kf = *(const short8*)&Ks[w * 16 + fr][dg * 32 + kg * 8];
            s[0] = __builtin_amdgcn_mfma_f32_16x16x32_bf16(qf[0][dg], kf, s[0], 0, 0, 0);
            s[1] = __builtin_amdgcn_mfma_f32_16x16x32_bf16(qf[1][dg], kf, s[1], 0, 0, 0);
        }

        #pragma unroll
        for (int qs = 0; qs < 2; ++qs) {
            float rmax[4];
            #pragma unroll
            for (int r = 0; r < 4; ++r) rmax[r] = s[qs][r] * scale;
            #pragma unroll
            for (int off = 1; off < 16; off <<= 1)
                #pragma unroll
                for (int r = 0; r < 4; ++r)
                    rmax[r] = fmaxf(rmax[r], __shfl_xor(rmax[r], off));
            if (fr == 0)
                #pragma unroll
                for (int r = 0; r < 4; ++r)
                    wmax[qs * 16 + kg * 4 + r][w] = rmax[r];
        }
        __syncthreads();

        float sc_my[4];
        #pragma unroll
        for (int qs = 0; qs < 2; ++qs) {
            float psum[4];
            #pragma unroll
            for (int r = 0; r < 4; ++r) {
                int row = qs * 16 + kg * 4 + r;
                float4 wm = *(const float4*)&wmax[row][0];
                float gm = fmaxf(fmaxf(wm.x, wm.y), fmaxf(wm.z, wm.w));
                float mnew = fmaxf(m[qs][r], gm);
                float scr = __expf(m[qs][r] - mnew);
                float p = __expf(s[qs][r] * scale - mnew);
                m[qs][r] = mnew;
                lsum[qs][r] *= scr;
                if (qs == myqs) sc_my[r] = scr;
                Ps[row][w * 16 + fr] = f2bf(p);
                psum[r] = p;
            }
            #pragma unroll
            for (int off = 1; off < 16; off <<= 1)
                #pragma unroll
                for (int r = 0; r < 4; ++r)
                    psum[r] += __shfl_xor(psum[r], off);
            if (fr == 0)
                #pragma unroll
                for (int r = 0; r < 4; ++r)
                    wsum[qs * 16 + kg * 4 + r][w] = psum[r];
        }
        __syncthreads();

        #pragma unroll
        for (int qs = 0; qs < 2; ++qs)
            #pragma unroll
            for (int r = 0; r < 4; ++r) {
                float4 wsv = *(const float4*)&wsum[qs * 16 + kg * 4 + r][0];
                lsum[qs][r] += wsv.x + wsv.y + wsv.z + wsv.w;
            }

        #pragma unroll
        for (int ds = 0; ds < 3; ++ds)
            #pragma unroll
            for (int r = 0; r < 4; ++r)
                acc_o[ds][r] *= sc_my[r];
        #pragma unroll
        for (int kk = 0; kk < 2; ++kk) {
            short8 pf = *(const short8*)&Ps[myqs * 16 + fr][kk * 32 + kg * 8];
            #pragma unroll
            for (int ds = 0; ds < 3; ++ds) {
                short8 vf = *(const short8*)&Vt[d0 + ds * 16 + fr][kk * 32 + kg * 8];
                acc_o[ds] = __builtin_amdgcn_mfma_f32_16x16x32_bf16(pf, vf, acc_o[ds], 0, 0, 0);
            }
        }
    }

    #pragma unroll
    for (int r = 0; r < 4; ++r) {
        float inv = 1.f / lsum[myqs][r];
        int q = row0 + myqs * 16 + kg * 4 + r;
        #pragma unroll
        for (int ds = 0; ds < 3; ++ds) {
            int d = h * 96 + d0 + ds * 16 + fr;
            ao[(size_t)q * C_S + d] = f2bf(acc_o[ds][r] * inv);
        }
    }
}

// ---------------------------------------------------------------------------
// two-rows-per-block LN helper (threads 0-127 row A, 128-255 row B)
__device__ __forceinline__ float row_reduce2(float v, volatile float* red, int tid)
{
    #pragma unroll
    for (int o = 32; o > 0; o >>= 1) v += __shfl_down(v, o);
    if ((tid & 63) == 0) red[tid >> 6] = v;
    __syncthreads();
    int rw = (tid >> 7) * 2;
    float r = red[rw] + red[rw + 1];
    __syncthreads();
    return r;
}

// ---------------------------------------------------------------------------
__device__ __forceinline__ void cvt_chunk(
    int c, int tid,
    const float* in_w, const float* out_w, const float* ff1_w, const float* ff2_w,
    __hip_bfloat16* winb, __hip_bfloat16* woutb,
    __hip_bfloat16* wf1b, __hip_bfloat16* wf2b)
{
    size_t e8 = (size_t)c * 256 + tid;   // 221184 total = 864 chunks x 256
    const float* src; __hip_bfloat16* dst; size_t off;
    if (e8 < 55296)       { src = in_w;  dst = winb;  off = e8; }
    else if (e8 < 73728)  { src = out_w; dst = woutb; off = e8 - 55296; }
    else if (e8 < 147456) { src = ff1_w; dst = wf1b;  off = e8 - 73728; }
    else                  { src = ff2_w; dst = wf2b;  off = e8 - 147456; }
    float4 a = *(const float4*)(src + off * 8);
    float4 b = *(const float4*)(src + off * 8 + 4);
    *(short8*)(dst + off * 8) = pack8(a, b);
}

// ---------------------------------------------------------------------------
__global__ __launch_bounds__(256, 2) void k_mega(
    const float* __restrict__ x_noisy, const float* __restrict__ s,
    const float* __restrict__ sigma, const int* __restrict__ a2t,
    const float* __restrict__ fourier_w, const float* __restrict__ fourier_b,
    const float* __restrict__ ns_w, const float* __restrict__ ns_b,
    const float* __restrict__ lns_g, const float* __restrict__ lns_b,
    const float* __restrict__ ce_w, const float* __restrict__ ce_b,
    const float* __restrict__ in_w, const float* __restrict__ in_b,
    const float* __restrict__ out_w, const float* __restrict__ out_b,
    const float* __restrict__ ffln_g, const float* __restrict__ ffln_b,
    const float* __restrict__ ff1_w, const float* __restrict__ ff1_b,
    const float* __restrict__ ff2_w, const float* __restrict__ ff2_b,
    const float* __restrict__ co_w, const float* __restrict__ co_b,
    float* __restrict__ ws, float* __restrict__ out)
{
    __shared__ SMem smem;
    cg::grid_group grid = cg::this_grid();
    int bid = blockIdx.x, tid = threadIdx.x;

    float* segx   = ws + OFF_SEGX;
    float* noise  = ws + OFF_NOISE;
    float* nsproj = ws + OFF_NSPROJ;
    float* tf1    = ws + OFF_TF1;
    float* tf2    = ws + OFF_TF2;
    float* tf3    = ws + OFF_TF3;
    __hip_bfloat16* qkvb  = (__hip_bfloat16*)(ws + OFF_QKV);
    __hip_bfloat16* aob   = (__hip_bfloat16*)(ws + OFF_AOB);
    __hip_bfloat16* lnhb  = (__hip_bfloat16*)(ws + OFF_LNHB);
    __hip_bfloat16* h1b   = (__hip_bfloat16*)(ws + OFF_H1B);
    __hip_bfloat16* winb  = (__hip_bfloat16*)(ws + OFF_WINB);
    __hip_bfloat16* woutb = (__hip_bfloat16*)(ws + OFF_WOUTB);
    __hip_bfloat16* wf1b  = (__hip_bfloat16*)(ws + OFF_WF1B);
    __hip_bfloat16* wf2b  = (__hip_bfloat16*)(ws + OFF_WF2B);
    __hip_bfloat16* tf1b  = (__hip_bfloat16*)(ws + OFF_TF1B);

    // ---- P0: weights->bf16 (864 chunks over 512 blocks; fixed R8 bug where
    //          only 432 chunks ran) | noise (352..367) | zero segx (368..383)
    {
        cvt_chunk(bid, tid, in_w, out_w, ff1_w, ff2_w, winb, woutb, wf1b, wf2b);
        if (bid < 352)
            cvt_chunk(bid + 512, tid, in_w, out_w, ff1_w, ff2_w,
                      winb, woutb, wf1b, wf2b);
        else if (bid < 368) {
            // noise[o] = fb[o] + sum_k emb[k]*fw[o][k]; 16 outs/block, 16 lanes/out
            float sg = sigma[0];
            int o = (bid - 352) * 16 + (tid >> 4);
            int l16 = tid & 15;
            float acc = 0.f;
            for (int j = 0; j < 16; ++j) {
                int k = l16 + j * 16;
                int kk = k & 127;
                float frq = __expf(-6.9077553f * (float)kk * (1.f / 128.f));
                float x = sg * frq;
                float e = (k < 128) ? cosf(x) : sinf(x);
                acc += e * fourier_w[(size_t)o * 256 + k];
            }
            #pragma unroll
            for (int o2 = 8; o2 > 0; o2 >>= 1) acc += __shfl_xor(acc, o2);
            if (l16 == 0) noise[o] = acc + fourier_b[o];
        } else if (bid < 384) {
            segx[(bid - 368) * 256 + tid] = 0.f;
        }
    }
    grid.sync();

    // ---- P1: segsum (0..95) | nsproj (96..119) ----
    if (bid < 96) {
        int a = bid * 256 + tid;
        int t = a2t[a];
        atomicAdd(&segx[t * 4 + 0], x_noisy[a * 3 + 0]);
        atomicAdd(&segx[t * 4 + 1], x_noisy[a * 3 + 1]);
        atomicAdd(&segx[t * 4 + 2], x_noisy[a * 3 + 2]);
        atomicAdd(&segx[t * 4 + 3], 1.f);
    } else if (bid < 120) {
        int o = (bid - 96) * 16 + (tid >> 4);
        int l16 = tid & 15;
        float acc = 0.f;
        for (int j = 0; j < 16; ++j) {
            int k = l16 + j * 16;
            acc += noise[k] * ns_w[(size_t)o * 256 + k];
        }
        #pragma unroll
        for (int o2 = 8; o2 > 0; o2 >>= 1) acc += __shfl_xor(acc, o2);
        if (l16 == 0) nsproj[o] = acc + ns_b[o];
    }
    grid.sync();

    // ---- P2: tokenfeat (2 rows/block) -> tf1 f32 + tf1b bf16 ----
    {
        int row = bid * 2 + (tid >> 7);
        int t128 = tid & 127;
        const float* sr = s + (size_t)row * 384;
        float x0 = sr[t128], x1 = sr[t128 + 128], x2 = sr[t128 + 256];
        float mean = row_reduce2(x0 + x1 + x2, smem.red, tid) * (1.f / 384.f);
        float d0 = x0 - mean, d1 = x1 - mean, d2 = x2 - mean;
        float var = row_reduce2(d0 * d0 + d1 * d1 + d2 * d2, smem.red, tid) * (1.f / 384.f);
        float rstd = rsqrtf(var + 1e-5f);
        float cnt = segx[row * 4 + 3];
        float mx0 = 0.f, mx1 = 0.f, mx2 = 0.f;
        int has = cnt > 0.f;
        if (has) {
            float ic = 1.f / cnt;
            mx0 = segx[row * 4 + 0] * ic;
            mx1 = segx[row * 4 + 1] * ic;
            mx2 = segx[row * 4 + 2] * ic;
        }
        float xs[3] = {d0, d1, d2};
        #pragma unroll
        for (int l = 0; l < 3; l++) {
            int c = t128 + l * 128;
            float v = xs[l] * rstd * lns_g[c] + lns_b[c] + nsproj[c];
            if (has)
                v += mx0 * ce_w[c * 3 + 0] + mx1 * ce_w[c * 3 + 1]
                   + mx2 * ce_w[c * 3 + 2] + ce_b[c];
            tf1[(size_t)row * 384 + c] = v;
            tf1b[(size_t)row * 384 + c] = f2bf(v);
        }
    }
    grid.sync();

    // ---- P3: qkv = tf1 @ in_w^T + in_b -> bf16 (288 tiles) ----
    if (bid < 288)
        gemm_tile<0, false, true>(smem, tf1b, winb, in_b, nullptr, nullptr, qkvb,
                                  1152, 384, (bid / 18) * 64, (bid % 18) * 64, tid);
    grid.sync();

    // ---- P4: MFMA flash attention (128 blocks) ----
    if (bid < 128)
        attn_tile(smem, qkvb, aob, (bid & 31) * 32, bid >> 5, tid);
    grid.sync();

    // ---- P5: tf2 = tf1 + ao @ out_w^T + out_b (96 tiles, f32) ----
    if (bid < 96)
        gemm_tile<0, true, false>(smem, aob, woutb, out_b, tf1, tf2, nullptr,
                                  384, 384, (bid / 6) * 64, (bid % 6) * 64, tid);
    grid.sync();

    // ---- P6: lnh = LN(tf2)*g+b -> bf16 (2 rows/block) ----
    {
        int row = bid * 2 + (tid >> 7);
        int t128 = tid & 127;
        const float* sr = tf2 + (size_t)row * 384;
        float x0 = sr[t128], x1 = sr[t128 + 128], x2 = sr[t128 + 256];
        float mean = row_reduce2(x0 + x1 + x2, smem.red, tid) * (1.f / 384.f);
        float d0 = x0 - mean, d1 = x1 - mean, d2 = x2 - mean;
        float var = row_reduce2(d0 * d0 + d1 * d1 + d2 * d2, smem.red, tid) * (1.f / 384.f);
        float rstd = rsqrtf(var + 1e-5f);
        float xs[3] = {d0, d1, d2};
        #pragma unroll
        for (int l = 0; l < 3; l++) {
            int c = t128 + l * 128;
            lnhb[(size_t)row * 384 + c] = f2bf(xs[l] * rstd * ffln_g[c] + ffln_b[c]);
        }
    }
    grid.sync();

    // ---- P7: h1 = silu(lnh @ ff1_w^T + ff1_b) -> bf16 (384 tiles) ----
    if (bid < 384)
        gemm_tile<1, false, true>(smem, lnhb, wf1b, ff1_b, nullptr, nullptr, h1b,
                                  1536, 384, (bid / 24) * 64, (bid % 24) * 64, tid);
    grid.sync();

    // ---- P8: tf3 = tf2 + h1 @ ff2_w^T + ff2_b (96 tiles, f32) ----
    if (bid < 96)
        gemm_tile<0, true, false>(smem, h1b, wf2b, ff2_b, tf2, tf3, nullptr,
                                  384, 1536, (bid / 6) * 64, (bid % 6) * 64, tid);
    grid.sync();

    // ---- P9: out[a] = tf3[idx[a]] . co_w^T + co_b (wave per atom) ----
    {
        int lane = tid & 63;
        int stride = gridDim.x * 4;
        for (int a = bid * 4 + (tid >> 6); a < N_ATOM; a += stride) {
            const float* base = tf3 + (size_t)a2t[a] * 384;
            float a0 = 0.f, a1 = 0.f, a2 = 0.f;
            #pragma unroll
            for (int i = 0; i < 6; ++i) {
                int c = lane + i * 64;
                float v = base[c];
                a0 += v * co_w[c];
                a1 += v * co_w[384 + c];
                a2 += v * co_w[768 + c];
            }
            #pragma unroll
            for (int off = 32; off > 0; off >>= 1) {
                a0 += __shfl_down(a0, off);
                a1 += __shfl_down(a1, off);
                a2 += __shfl_down(a2, off);
            }
            if (lane == 0) {
                out[a * 3 + 0] = a0 + co_b[0];
                out[a * 3 + 1] = a1 + co_b[1];
                out[a * 3 + 2] = a2 + co_b[2];
            }
        }
    }
}

// ---------------------------------------------------------------------------
extern "C" void kernel_launch(void* const* d_in, const int* in_sizes, int n_in,
                              void* d_out, int out_size, void* d_ws, size_t ws_size,
                              hipStream_t stream)
{
    const float* x_noisy   = (const float*)d_in[0];
    const float* s         = (const float*)d_in[1];
    // d_in[2] = z : dead code in the reference (z_cond unused) -> never read
    const float* sigma     = (const float*)d_in[3];
    const int*   a2t       = (const int*)d_in[4];
    const float* fourier_w = (const float*)d_in[5];
    const float* fourier_b = (const float*)d_in[6];
    const float* ns_w      = (const float*)d_in[7];
    const float* ns_b      = (const float*)d_in[8];
    const float* lns_g     = (const float*)d_in[11];
    const float* lns_b     = (const float*)d_in[12];
    const float* ce_w      = (const float*)d_in[15];
    const float* ce_b      = (const float*)d_in[16];
    const float* in_w      = (const float*)d_in[17];
    const float* in_b      = (const float*)d_in[18];
    const float* out_w     = (const float*)d_in[19];
    const float* out_b     = (const float*)d_in[20];
    const float* ffln_g    = (const float*)d_in[21];
    const float* ffln_b    = (const float*)d_in[22];
    const float* ff1_w     = (const float*)d_in[23];
    const float* ff1_b     = (const float*)d_in[24];
    const float* ff2_w     = (const float*)d_in[25];
    const float* ff2_b     = (const float*)d_in[26];
    const float* co_w      = (const float*)d_in[27];
    const float* co_b      = (const float*)d_in[28];

    float* ws  = (float*)d_ws;
    float* outp = (float*)d_out;

    void* args[] = {
        (void*)&x_noisy, (void*)&s, (void*)&sigma, (void*)&a2t,
        (void*)&fourier_w, (void*)&fourier_b, (void*)&ns_w, (void*)&ns_b,
        (void*)&lns_g, (void*)&lns_b, (void*)&ce_w, (void*)&ce_b,
        (void*)&in_w, (void*)&in_b, (void*)&out_w, (void*)&out_b,
        (void*)&ffln_g, (void*)&ffln_b, (void*)&ff1_w, (void*)&ff1_b,
        (void*)&ff2_w, (void*)&ff2_b, (void*)&co_w, (void*)&co_b,
        (void*)&ws, (void*)&outp
    };
    hipLaunchCooperativeKernel((void*)k_mega, dim3(512), dim3(256),
                               args, 0, stream);
}

// Round 11
// 168.602 us; speedup vs baseline: 3.7663x; 3.7663x over previous
//
#include <hip/hip_runtime.h>
#include <hip/hip_bf16.h>
#include <math.h>

#define N_TOK 1024
#define N_ATOM 24576
#define C_S 384
#define NH 4
#define HD 96

typedef __attribute__((ext_vector_type(8))) short short8;   // 8 bf16
typedef __attribute__((ext_vector_type(4))) float f32x4;

// ---- workspace layout (float-slot offsets, 16B-aligned, end-to-end audited) ----
#define OFF_SEGX   0u          // 4096 f32
#define OFF_TOUT   4096u       // 3328 f32 (3072 used + pad)
#define OFF_NSPROJ 7424u       // 512 f32 (384 used)
#define OFF_TF1    8192u       // 393216 f32            -> ends 401408
#define OFF_TF2    401408u     // 393216 f32            -> ends 794624
#define OFF_QKV    794624u     // qkv bf16 1024x1152 = 589824 f32 -> ends 1384448
#define OFF_AOB    1384448u    // ao bf16 1024x384 = 196608 f32   -> ends 1581056
#define OFF_H1B    1581056u    // h1 bf16 1024x1536 = 786432 f32  -> ends 2367488
#define OFF_WINB   2367488u    // in_w bf16 1152x384 = 221184 f32 -> ends 2588672
#define OFF_WOUTB  2588672u    // out_w bf16 384x384 = 73728 f32  -> ends 2662400
#define OFF_WF1B   2662400u    // ff1_w bf16 1536x384 = 294912    -> ends 2957312
#define OFF_WF2B   2957312u    // ff2_w bf16 1536x384 = 294912    -> ends 3252224

__device__ inline __hip_bfloat16 f2bf(float x) { return __float2bfloat16(x); }
union BFPack { short8 v; __hip_bfloat16 h[8]; };
__device__ inline short8 pack8(float4 a, float4 b)
{
    BFPack p;
    p.h[0] = f2bf(a.x); p.h[1] = f2bf(a.y); p.h[2] = f2bf(a.z); p.h[3] = f2bf(a.w);
    p.h[4] = f2bf(b.x); p.h[5] = f2bf(b.y); p.h[6] = f2bf(b.z); p.h[7] = f2bf(b.w);
    return p.v;
}

// ---------------------------------------------------------------------------
// k_prep: blocks 0..863 weights->bf16 (block 0 zeroes segx+tout) | 864 setup
__global__ __launch_bounds__(256) void k_prep(
    const float* __restrict__ in_w, const float* __restrict__ out_w,
    const float* __restrict__ ff1_w, const float* __restrict__ ff2_w,
    __hip_bfloat16* __restrict__ winb, __hip_bfloat16* __restrict__ woutb,
    __hip_bfloat16* __restrict__ wf1b, __hip_bfloat16* __restrict__ wf2b,
    const float* __restrict__ sigma,
    const float* __restrict__ fw, const float* __restrict__ fb,
    const float* __restrict__ nsw, const float* __restrict__ nsb,
    float* __restrict__ nsproj_out, float* __restrict__ zero_base)
{
    __shared__ float emb[256];
    __shared__ float noise[256];
    int tid = threadIdx.x;
    int bid = blockIdx.x;

    if (bid == 864) {           // ---- fourier -> noise -> nsproj ----
        float sg = sigma[0];
        if (tid < 128) {
            float fr = expf(-logf(1000.f) * (float)tid / 128.f);
            float x = sg * fr;
            emb[tid]       = cosf(x);
            emb[tid + 128] = sinf(x);
        }
        __syncthreads();
        {
            const float* wr = fw + (size_t)tid * 256;
            float acc = fb[tid];
            for (int i = 0; i < 256; i++) acc += emb[i] * wr[i];
            noise[tid] = acc;
        }
        __syncthreads();
        for (int o = tid; o < 384; o += 256) {
            const float* wr = nsw + (size_t)o * 256;
            float acc = nsb[o];
            for (int i = 0; i < 256; i++) acc += noise[i] * wr[i];
            nsproj_out[o] = acc;
        }
        return;
    }
    if (bid == 0) {             // zero segx [0,4096) + tout [4096,7424)
        for (int i = tid; i < 7424; i += 256) zero_base[i] = 0.f;
    }
    size_t e8 = (size_t)bid * 256 + tid;
    const float* src; __hip_bfloat16* dst; size_t off;
    if (e8 < 55296)       { src = in_w;  dst = winb;  off = e8; }
    else if (e8 < 73728)  { src = out_w; dst = woutb; off = e8 - 55296; }
    else if (e8 < 147456) { src = ff1_w; dst = wf1b;  off = e8 - 73728; }
    else                  { src = ff2_w; dst = wf2b;  off = e8 - 147456; }
    float4 a = *(const float4*)(src + off * 8);
    float4 b = *(const float4*)(src + off * 8 + 4);
    *(short8*)(dst + off * 8) = pack8(a, b);
}

// ---------------------------------------------------------------------------
__global__ __launch_bounds__(256) void k_segsum(
    const float* __restrict__ x, const int* __restrict__ idx,
    float* __restrict__ segx)
{
    int a = blockIdx.x * 256 + threadIdx.x;
    if (a < N_ATOM) {
        int t = idx[a];
        atomicAdd(&segx[t * 4 + 0], x[a * 3 + 0]);
        atomicAdd(&segx[t * 4 + 1], x[a * 3 + 1]);
        atomicAdd(&segx[t * 4 + 2], x[a * 3 + 2]);
        atomicAdd(&segx[t * 4 + 3], 1.f);
    }
}

// ---------------------------------------------------------------------------
// LN-fused MFMA GEMM v2 — plain 18KB LDS (2 blk/CU), stats-in-registers
// (stats thread == staging thread per row), all-float4 channel loads.
// MODE 0: A = tokenfeat(s,...) -> qkv bf16; blockIdx.x==0 writes tf1 f32.
// MODE 1: A = LN(tf2)*g+b -> ff1 with silu epilogue -> h1 bf16.
template <int MODE>
__global__ __launch_bounds__(256) void k_lngemm2(
    const float* __restrict__ X, const __hip_bfloat16* __restrict__ W,
    const float* __restrict__ bias,
    const float* __restrict__ g, const float* __restrict__ b,
    const float* __restrict__ segx, const float* __restrict__ nsproj,
    const float* __restrict__ ce_w, const float* __restrict__ ce_b,
    float* __restrict__ tf1out, __hip_bfloat16* __restrict__ OUT, int N)
{
    __shared__ __hip_bfloat16 As[64][72];
    __shared__ __hip_bfloat16 Bs[64][72];

    int tid = threadIdx.x;
    int bm = blockIdx.y * 64, bn = blockIdx.x * 64;
    int sr = tid >> 2, sc4 = tid & 3;    // staging: row sr, col-quarter sc4

    const float* xrow = X + (size_t)(bm + sr) * 384;
    // ---- row stats: 4 threads per row, shfl over lane^1, lane^2 ----
    const float* xr = xrow + sc4 * 96;
    float s1 = 0.f, s2 = 0.f;
    #pragma unroll
    for (int i = 0; i < 24; ++i) {
        float4 v = *(const float4*)(xr + 4 * i);
        s1 += v.x + v.y + v.z + v.w;
        s2 += v.x * v.x + v.y * v.y + v.z * v.z + v.w * v.w;
    }
    s1 += __shfl_xor(s1, 1); s1 += __shfl_xor(s1, 2);
    s2 += __shfl_xor(s2, 1); s2 += __shfl_xor(s2, 2);
    float mean = s1 * (1.f / 384.f);
    float rstd = rsqrtf(s2 * (1.f / 384.f) - mean * mean + 1e-5f);

    float mx0 = 0.f, mx1 = 0.f, mx2 = 0.f;
    bool has = false;
    if (MODE == 0) {
        float cnt = segx[(bm + sr) * 4 + 3];
        has = cnt > 0.f;
        if (has) {
            float ic = 1.f / cnt;
            mx0 = segx[(bm + sr) * 4 + 0] * ic;
            mx1 = segx[(bm + sr) * 4 + 1] * ic;
            mx2 = segx[(bm + sr) * 4 + 2] * ic;
        }
    }

    // ---- K-loop with fused normalize-on-stage ----
    int w = tid >> 6, lane = tid & 63;
    int wr = (w >> 1) * 32, wc = (w & 1) * 32;
    int fr = lane & 15, kg = lane >> 4;

    f32x4 acc[2][2] = {};
    for (int k0 = 0; k0 < 384; k0 += 64) {
        int c0 = k0 + sc4 * 16;
        short8 apack[2];
        float fv[16];
        #pragma unroll
        for (int hh = 0; hh < 2; ++hh) {
            int c = c0 + hh * 8;
            float xv[8], gv[8], bv[8], vv[8];
            *(float4*)&xv[0] = *(const float4*)(xrow + c);
            *(float4*)&xv[4] = *(const float4*)(xrow + c + 4);
            *(float4*)&gv[0] = *(const float4*)(g + c);
            *(float4*)&gv[4] = *(const float4*)(g + c + 4);
            *(float4*)&bv[0] = *(const float4*)(b + c);
            *(float4*)&bv[4] = *(const float4*)(b + c + 4);
            #pragma unroll
            for (int j = 0; j < 8; ++j)
                vv[j] = (xv[j] - mean) * rstd * gv[j] + bv[j];
            if (MODE == 0) {
                float nv[8], cb[8], ce[24];
                *(float4*)&nv[0] = *(const float4*)(nsproj + c);
                *(float4*)&nv[4] = *(const float4*)(nsproj + c + 4);
                *(float4*)&cb[0] = *(const float4*)(ce_b + c);
                *(float4*)&cb[4] = *(const float4*)(ce_b + c + 4);
                #pragma unroll
                for (int q = 0; q < 6; ++q)
                    *(float4*)&ce[q * 4] = *(const float4*)(ce_w + c * 3 + q * 4);
                #pragma unroll
                for (int j = 0; j < 8; ++j) {
                    vv[j] += nv[j];
                    if (has)
                        vv[j] += mx0 * ce[j * 3 + 0] + mx1 * ce[j * 3 + 1]
                               + mx2 * ce[j * 3 + 2] + cb[j];
                }
            }
            BFPack p;
            #pragma unroll
            for (int j = 0; j < 8; ++j) { p.h[j] = f2bf(vv[j]); fv[hh * 8 + j] = vv[j]; }
            apack[hh] = p.v;
        }
        const __hip_bfloat16* wg = W + (size_t)(bn + sr) * 384 + c0;
        short8 bb0 = *(const short8*)(wg + 0);
        short8 bb1 = *(const short8*)(wg + 8);
        __syncthreads();             // prev frag reads done
        *(short8*)&As[sr][sc4 * 16 + 0] = apack[0];
        *(short8*)&As[sr][sc4 * 16 + 8] = apack[1];
        *(short8*)&Bs[sr][sc4 * 16 + 0] = bb0;
        *(short8*)&Bs[sr][sc4 * 16 + 8] = bb1;
        __syncthreads();
        if (MODE == 0 && blockIdx.x == 0) {
            float* dst = tf1out + (size_t)(bm + sr) * 384 + c0;
            *(float4*)(dst + 0)  = *(float4*)&fv[0];
            *(float4*)(dst + 4)  = *(float4*)&fv[4];
            *(float4*)(dst + 8)  = *(float4*)&fv[8];
            *(float4*)(dst + 12) = *(float4*)&fv[12];
        }

        short8 af[2][2], bf[2][2];
        #pragma unroll
        for (int i = 0; i < 2; ++i)
            #pragma unroll
            for (int kh = 0; kh < 2; ++kh) {
                af[i][kh] = *(const short8*)&As[wr + i * 16 + fr][kh * 32 + kg * 8];
                bf[i][kh] = *(const short8*)&Bs[wc + i * 16 + fr][kh * 32 + kg * 8];
            }
        #pragma unroll
        for (int kh = 0; kh < 2; ++kh)
            #pragma unroll
            for (int i = 0; i < 2; ++i)
                #pragma unroll
                for (int j = 0; j < 2; ++j)
                    acc[i][j] = __builtin_amdgcn_mfma_f32_16x16x32_bf16(
                        af[i][kh], bf[j][kh], acc[i][j], 0, 0, 0);
    }

    // ---- epilogue (C/D: col=lane&15, row=(lane>>4)*4+reg) ----
    #pragma unroll
    for (int i = 0; i < 2; ++i)
        #pragma unroll
        for (int j = 0; j < 2; ++j) {
            int n = bn + wc + j * 16 + fr;
            float bsv = bias[n];
            #pragma unroll
            for (int r = 0; r < 4; ++r) {
                int m = bm + wr + i * 16 + kg * 4 + r;
                float v = acc[i][j][r] + bsv;
                if (MODE == 1) v = v / (1.f + __expf(-v));   // silu
                OUT[(size_t)m * N + n] = f2bf(v);
            }
        }
}

// ---------------------------------------------------------------------------
// bf16 MFMA GEMM, f32 out + residual (outproj): C = A @ W^T + bias + res
__global__ __launch_bounds__(256) void k_gemm_res(
    const __hip_bfloat16* __restrict__ A, const __hip_bfloat16* __restrict__ W,
    const float* __restrict__ bias, const float* __restrict__ res,
    float* __restrict__ C, int M, int N, int K)
{
    __shared__ __hip_bfloat16 As[64][72];
    __shared__ __hip_bfloat16 Bs[64][72];

    int tid = threadIdx.x;
    int bm = blockIdx.y * 64, bn = blockIdx.x * 64;
    int w = tid >> 6, lane = tid & 63;
    int wr = (w >> 1) * 32, wc = (w & 1) * 32;
    int fr = lane & 15, kg = lane >> 4;
    int sr = tid >> 2, sc = (tid & 3) << 4;

    f32x4 acc[2][2] = {};
    for (int k0 = 0; k0 < K; k0 += 64) {
        const __hip_bfloat16* ag = A + (size_t)(bm + sr) * K + k0 + sc;
        const __hip_bfloat16* wg = W + (size_t)(bn + sr) * K + k0 + sc;
        short8 a0 = *(const short8*)(ag + 0);
        short8 a1 = *(const short8*)(ag + 8);
        short8 b0 = *(const short8*)(wg + 0);
        short8 b1 = *(const short8*)(wg + 8);
        __syncthreads();
        *(short8*)&As[sr][sc + 0] = a0;
        *(short8*)&As[sr][sc + 8] = a1;
        *(short8*)&Bs[sr][sc + 0] = b0;
        *(short8*)&Bs[sr][sc + 8] = b1;
        __syncthreads();

        short8 af[2][2], bf[2][2];
        #pragma unroll
        for (int i = 0; i < 2; ++i)
            #pragma unroll
            for (int kh = 0; kh < 2; ++kh) {
                af[i][kh] = *(const short8*)&As[wr + i * 16 + fr][kh * 32 + kg * 8];
                bf[i][kh] = *(const short8*)&Bs[wc + i * 16 + fr][kh * 32 + kg * 8];
            }
        #pragma unroll
        for (int kh = 0; kh < 2; ++kh)
            #pragma unroll
            for (int i = 0; i < 2; ++i)
                #pragma unroll
                for (int j = 0; j < 2; ++j)
                    acc[i][j] = __builtin_amdgcn_mfma_f32_16x16x32_bf16(
                        af[i][kh], bf[j][kh], acc[i][j], 0, 0, 0);
    }

    #pragma unroll
    for (int i = 0; i < 2; ++i)
        #pragma unroll
        for (int j = 0; j < 2; ++j) {
            int n = bn + wc + j * 16 + fr;
            float bv = bias[n];
            #pragma unroll
            for (int r = 0; r < 4; ++r) {
                int m = bm + wr + i * 16 + kg * 4 + r;
                C[(size_t)m * N + n] = acc[i][j][r] + bv + res[(size_t)m * N + n];
            }
        }
}

// ---------------------------------------------------------------------------
// ff2 GEMM with tout epilogue: tf3 never materialized; each block reduces its
// tile's contribution to tout[m][jj] = sum_n tf3[m][n]*co_w[jj][n] (f32 atomics)
__global__ __launch_bounds__(256) void k_gemm_tout(
    const __hip_bfloat16* __restrict__ A, const __hip_bfloat16* __restrict__ W,
    const float* __restrict__ bias, const float* __restrict__ res,
    const float* __restrict__ co_w, float* __restrict__ tout, int K)
{
    __shared__ __hip_bfloat16 As[64][72];
    __shared__ __hip_bfloat16 Bs[64][72];

    int tid = threadIdx.x;
    int bm = blockIdx.y * 64, bn = blockIdx.x * 64;
    int w = tid >> 6, lane = tid & 63;
    int wr = (w >> 1) * 32, wc = (w & 1) * 32;
    int fr = lane & 15, kg = lane >> 4;
    int sr = tid >> 2, sc = (tid & 3) << 4;

    f32x4 acc[2][2] = {};
    for (int k0 = 0; k0 < K; k0 += 64) {
        const __hip_bfloat16* ag = A + (size_t)(bm + sr) * K + k0 + sc;
        const __hip_bfloat16* wg = W + (size_t)(bn + sr) * K + k0 + sc;
        short8 a0 = *(const short8*)(ag + 0);
        short8 a1 = *(const short8*)(ag + 8);
        short8 b0 = *(const short8*)(wg + 0);
        short8 b1 = *(const short8*)(wg + 8);
        __syncthreads();
        *(short8*)&As[sr][sc + 0] = a0;
        *(short8*)&As[sr][sc + 8] = a1;
        *(short8*)&Bs[sr][sc + 0] = b0;
        *(short8*)&Bs[sr][sc + 8] = b1;
        __syncthreads();

        short8 af[2][2], bf[2][2];
        #pragma unroll
        for (int i = 0; i < 2; ++i)
            #pragma unroll
            for (int kh = 0; kh < 2; ++kh) {
                af[i][kh] = *(const short8*)&As[wr + i * 16 + fr][kh * 32 + kg * 8];
                bf[i][kh] = *(const short8*)&Bs[wc + i * 16 + fr][kh * 32 + kg * 8];
            }
        #pragma unroll
        for (int kh = 0; kh < 2; ++kh)
            #pragma unroll
            for (int i = 0; i < 2; ++i)
                #pragma unroll
                for (int j = 0; j < 2; ++j)
                    acc[i][j] = __builtin_amdgcn_mfma_f32_16x16x32_bf16(
                        af[i][kh], bf[j][kh], acc[i][j], 0, 0, 0);
    }

    // epilogue: v = acc + bias + res (full tf3 value), reduce v*co_w over n
    float part[2][4][3] = {};
    #pragma unroll
    for (int j = 0; j < 2; ++j) {
        int n = bn + wc + j * 16 + fr;
        float bv = bias[n];
        float c0 = co_w[n], c1 = co_w[384 + n], c2 = co_w[768 + n];
        #pragma unroll
        for (int i = 0; i < 2; ++i)
            #pragma unroll
            for (int r = 0; r < 4; ++r) {
                int m = bm + wr + i * 16 + kg * 4 + r;
                float v = acc[i][j][r] + bv + res[(size_t)m * 384 + n];
                part[i][r][0] += v * c0;
                part[i][r][1] += v * c1;
                part[i][r][2] += v * c2;
            }
    }
    #pragma unroll
    for (int off = 1; off < 16; off <<= 1)
        #pragma unroll
        for (int i = 0; i < 2; ++i)
            #pragma unroll
            for (int r = 0; r < 4; ++r)
                #pragma unroll
                for (int jj = 0; jj < 3; ++jj)
                    part[i][r][jj] += __shfl_xor(part[i][r][jj], off);
    if (fr == 0)
        #pragma unroll
        for (int i = 0; i < 2; ++i)
            #pragma unroll
            for (int r = 0; r < 4; ++r) {
                int m = bm + wr + i * 16 + kg * 4 + r;
                #pragma unroll
                for (int jj = 0; jj < 3; ++jj)
                    atomicAdd(&tout[m * 3 + jj], part[i][r][jj]);
            }
}

// ---------------------------------------------------------------------------
// MFMA flash attention (R5-proven): block = (32 Q-rows, head).
#define QB 32
#define TB 64

__global__ __launch_bounds__(256) void k_attn(
    const __hip_bfloat16* __restrict__ qkv, __hip_bfloat16* __restrict__ ao)
{
    __shared__ __hip_bfloat16 Ks[TB][104];
    __shared__ __hip_bfloat16 Vt[96][72];
    __shared__ __hip_bfloat16 Ps[QB][72];
    __shared__ float wmax[QB][4];
    __shared__ float wsum[QB][4];

    int tid = threadIdx.x;
    int w = tid >> 6, l = tid & 63;
    int fr = l & 15, kg = l >> 4;
    int row0 = blockIdx.x * QB;
    int h = blockIdx.y;
    const float scale = 0.1020620726f;   // 1/sqrt(96)

    short8 qf[2][3];
    #pragma unroll
    for (int qs = 0; qs < 2; ++qs)
        #pragma unroll
        for (int dg = 0; dg < 3; ++dg)
            qf[qs][dg] = *(const short8*)(qkv
                + (size_t)(row0 + qs * 16 + fr) * 1152 + h * 96 + dg * 32 + kg * 8);

    float m[2][4], lsum[2][4];
    #pragma unroll
    for (int qs = 0; qs < 2; ++qs)
        #pragma unroll
        for (int r = 0; r < 4; ++r) { m[qs][r] = -1e30f; lsum[qs][r] = 0.f; }

    const int myqs = w >> 1;
    const int d0 = (w & 1) * 48;
    f32x4 acc_o[3] = {};

    int st_t = tid >> 2, st_c = (tid & 3) * 24;
    int vt_t = tid & 63, vt_d = (tid >> 6) * 24;

    for (int tile = 0; tile < N_TOK / TB; ++tile) {
        int t0 = tile * TB;
        __syncthreads();
        {
            const __hip_bfloat16* src =
                qkv + (size_t)(t0 + st_t) * 1152 + 384 + h * 96 + st_c;
            short8 k0 = *(const short8*)(src);
            short8 k1 = *(const short8*)(src + 8);
            short8 k2 = *(const short8*)(src + 16);
            *(short8*)&Ks[st_t][st_c + 0]  = k0;
            *(short8*)&Ks[st_t][st_c + 8]  = k1;
            *(short8*)&Ks[st_t][st_c + 16] = k2;
        }
        {
            const __hip_bfloat16* src =
                qkv + (size_t)(t0 + vt_t) * 1152 + 768 + h * 96 + vt_d;
            BFPack p0, p1, p2;
            p0.v = *(const short8*)(src);
            p1.v = *(const short8*)(src + 8);
            p2.v = *(const short8*)(src + 16);
            #pragma unroll
            for (int j = 0; j < 8; ++j) {
                Vt[vt_d + j][vt_t]      = p0.h[j];
                Vt[vt_d + 8 + j][vt_t]  = p1.h[j];
                Vt[vt_d + 16 + j][vt_t] = p2.h[j];
            }
        }
        __syncthreads();

        f32x4 s[2] = {};
        #pragma unroll
        for (int dg = 0; dg < 3; ++dg) {
            short8 kf = *(const short8*)&Ks[w * 16 + fr][dg * 32 + kg * 8];
            s[0] = __builtin_amdgcn_mfma_f32_16x16x32_bf16(qf[0][dg], kf, s[0], 0, 0, 0);
            s[1] = __builtin_amdgcn_mfma_f32_16x16x32_bf16(qf[1][dg], kf, s[1], 0, 0, 0);
        }

        #pragma unroll
        for (int qs = 0; qs < 2; ++qs) {
            float rmax[4];
            #pragma unroll
            for (int r = 0; r < 4; ++r) rmax[r] = s[qs][r] * scale;
            #pragma unroll
            for (int off = 1; off < 16; off <<= 1)
                #pragma unroll
                for (int r = 0; r < 4; ++r)
                    rmax[r] = fmaxf(rmax[r], __shfl_xor(rmax[r], off));
            if (fr == 0)
                #pragma unroll
                for (int r = 0; r < 4; ++r)
                    wmax[qs * 16 + kg * 4 + r][w] = rmax[r];
        }
        __syncthreads();

        float sc_my[4];
        #pragma unroll
        for (int qs = 0; qs < 2; ++qs) {
            float psum[4];
            #pragma unroll
            for (int r = 0; r < 4; ++r) {
                int row = qs * 16 + kg * 4 + r;
                float4 wm = *(const float4*)&wmax[row][0];
                float gm = fmaxf(fmaxf(wm.x, wm.y), fmaxf(wm.z, wm.w));
                float mnew = fmaxf(m[qs][r], gm);
                float scr = __expf(m[qs][r] - mnew);
                float p = __expf(s[qs][r] * scale - mnew);
                m[qs][r] = mnew;
                lsum[qs][r] *= scr;
                if (qs == myqs) sc_my[r] = scr;
                Ps[row][w * 16 + fr] = f2bf(p);
                psum[r] = p;
            }
            #pragma unroll
            for (int off = 1; off < 16; off <<= 1)
                #pragma unroll
                for (int r = 0; r < 4; ++r)
                    psum[r] += __shfl_xor(psum[r], off);
            if (fr == 0)
                #pragma unroll
                for (int r = 0; r < 4; ++r)
                    wsum[qs * 16 + kg * 4 + r][w] = psum[r];
        }
        __syncthreads();

        #pragma unroll
        for (int qs = 0; qs < 2; ++qs)
            #pragma unroll
            for (int r = 0; r < 4; ++r) {
                float4 wsv = *(const float4*)&wsum[qs * 16 + kg * 4 + r][0];
                lsum[qs][r] += wsv.x + wsv.y + wsv.z + wsv.w;
            }

        #pragma unroll
        for (int ds = 0; ds < 3; ++ds)
            #pragma unroll
            for (int r = 0; r < 4; ++r)
                acc_o[ds][r] *= sc_my[r];
        #pragma unroll
        for (int kk = 0; kk < 2; ++kk) {
            short8 pf = *(const short8*)&Ps[myqs * 16 + fr][kk * 32 + kg * 8];
            #pragma unroll
            for (int ds = 0; ds < 3; ++ds) {
                short8 vf = *(const short8*)&Vt[d0 + ds * 16 + fr][kk * 32 + kg * 8];
                acc_o[ds] = __builtin_amdgcn_mfma_f32_16x16x32_bf16(pf, vf, acc_o[ds], 0, 0, 0);
            }
        }
    }

    #pragma unroll
    for (int r = 0; r < 4; ++r) {
        float inv = 1.f / lsum[myqs][r];
        int q = row0 + myqs * 16 + kg * 4 + r;
        #pragma unroll
        for (int ds = 0; ds < 3; ++ds) {
            int d = h * 96 + d0 + ds * 16 + fr;
            ao[(size_t)q * C_S + d] = f2bf(acc_o[ds][r] * inv);
        }
    }
}

// ---------------------------------------------------------------------------
// gather: out[a] = tout[idx[a]] + co_b   (12 B per atom)
__global__ __launch_bounds__(256) void k_gather(
    const float* __restrict__ tout, const int* __restrict__ idx,
    const float* __restrict__ co_b, float* __restrict__ out)
{
    int a = blockIdx.x * 256 + threadIdx.x;
    if (a < N_ATOM) {
        int t = idx[a];
        out[a * 3 + 0] = tout[t * 3 + 0] + co_b[0];
        out[a * 3 + 1] = tout[t * 3 + 1] + co_b[1];
        out[a * 3 + 2] = tout[t * 3 + 2] + co_b[2];
    }
}

// ---------------------------------------------------------------------------
extern "C" void kernel_launch(void* const* d_in, const int* in_sizes, int n_in,
                              void* d_out, int out_size, void* d_ws, size_t ws_size,
                              hipStream_t stream)
{
    const float* x_noisy   = (const float*)d_in[0];
    const float* s         = (const float*)d_in[1];
    // d_in[2] = z : dead code in the reference (z_cond unused) -> never read
    const float* sigma     = (const float*)d_in[3];
    const int*   a2t       = (const int*)d_in[4];
    const float* fourier_w = (const float*)d_in[5];
    const float* fourier_b = (const float*)d_in[6];
    const float* ns_w      = (const float*)d_in[7];
    const float* ns_b      = (const float*)d_in[8];
    const float* lns_g     = (const float*)d_in[11];
    const float* lns_b     = (const float*)d_in[12];
    const float* ce_w      = (const float*)d_in[15];
    const float* ce_b      = (const float*)d_in[16];
    const float* in_w      = (const float*)d_in[17];
    const float* in_b      = (const float*)d_in[18];
    const float* out_w     = (const float*)d_in[19];
    const float* out_b     = (const float*)d_in[20];
    const float* ffln_g    = (const float*)d_in[21];
    const float* ffln_b    = (const float*)d_in[22];
    const float* ff1_w     = (const float*)d_in[23];
    const float* ff1_b     = (const float*)d_in[24];
    const float* ff2_w     = (const float*)d_in[25];
    const float* ff2_b     = (const float*)d_in[26];
    const float* co_w      = (const float*)d_in[27];
    const float* co_b      = (const float*)d_in[28];

    float* ws  = (float*)d_ws;
    float* out = (float*)d_out;
    __hip_bfloat16* qkvb  = (__hip_bfloat16*)(ws + OFF_QKV);
    __hip_bfloat16* aob   = (__hip_bfloat16*)(ws + OFF_AOB);
    __hip_bfloat16* h1b   = (__hip_bfloat16*)(ws + OFF_H1B);
    __hip_bfloat16* winb  = (__hip_bfloat16*)(ws + OFF_WINB);
    __hip_bfloat16* woutb = (__hip_bfloat16*)(ws + OFF_WOUTB);
    __hip_bfloat16* wf1b  = (__hip_bfloat16*)(ws + OFF_WF1B);
    __hip_bfloat16* wf2b  = (__hip_bfloat16*)(ws + OFF_WF2B);

    // 1. prep: weights->bf16 | setup | zero segx+tout (block 0)
    hipLaunchKernelGGL(k_prep, dim3(865), dim3(256), 0, stream,
                       in_w, out_w, ff1_w, ff2_w, winb, woutb, wf1b, wf2b,
                       sigma, fourier_w, fourier_b, ns_w, ns_b,
                       ws + OFF_NSPROJ, ws);
    // 2. segment sums
    hipLaunchKernelGGL(k_segsum, dim3(96), dim3(256), 0, stream,
                       x_noisy, a2t, ws + OFF_SEGX);
    // 3. tokenfeat-fused qkv GEMM (blockIdx.x==0 writes tf1 f32)
    hipLaunchKernelGGL((k_lngemm2<0>), dim3(18, 16), dim3(256), 0, stream,
                       s, winb, in_b, lns_g, lns_b,
                       ws + OFF_SEGX, ws + OFF_NSPROJ, ce_w, ce_b,
                       ws + OFF_TF1, qkvb, 1152);
    // 4. MFMA flash attention
    hipLaunchKernelGGL(k_attn, dim3(N_TOK / QB, NH), dim3(256), 0, stream,
                       qkvb, aob);
    // 5. tf2 = tf1 + ao @ out_w^T + out_b  (f32)
    hipLaunchKernelGGL(k_gemm_res, dim3(6, 16), dim3(256), 0, stream,
                       aob, woutb, out_b, ws + OFF_TF1, ws + OFF_TF2,
                       1024, 384, 384);
    // 6. ffln-fused ff1 GEMM: h1 = silu(LN(tf2) @ ff1_w^T + ff1_b) -> bf16
    hipLaunchKernelGGL((k_lngemm2<1>), dim3(24, 16), dim3(256), 0, stream,
                       ws + OFF_TF2, wf1b, ff1_b, ffln_g, ffln_b,
                       nullptr, nullptr, nullptr, nullptr,
                       nullptr, h1b, 1536);
    // 7. ff2 GEMM + tout epilogue (tf3 never materialized)
    hipLaunchKernelGGL(k_gemm_tout, dim3(6, 16), dim3(256), 0, stream,
                       h1b, wf2b, ff2_b, ws + OFF_TF2, co_w,
                       ws + OFF_TOUT, 1536);
    // 8. gather
    hipLaunchKernelGGL(k_gather, dim3(96), dim3(256), 0, stream,
                       ws + OFF_TOUT, a2t, co_b, out);
}

// Round 12
// 140.180 us; speedup vs baseline: 4.5299x; 1.2028x over previous
//
#include <hip/hip_runtime.h>
#include <hip/hip_bf16.h>
#include <math.h>

#define N_TOK 1024
#define N_ATOM 24576
#define C_S 384
#define NH 4
#define HD 96

typedef __attribute__((ext_vector_type(8))) short short8;   // 8 bf16
typedef __attribute__((ext_vector_type(4))) float f32x4;

// ---- workspace layout (float-slot offsets; audited: each = prev + size) ----
#define OFF_SEGX   0u          // 4096                  -> ends 4096
#define OFF_TOUT   4096u       // 3328 (3072 used)      -> ends 7424
#define OFF_RSTAT  7424u       // 2048 (1024x2)         -> ends 9472
#define OFF_NSPROJ 9472u       // 512 (384 used)        -> ends 9984
#define OFF_TF1    9984u       // 393216 f32            -> ends 403200
#define OFF_TF2    403200u     // 393216 f32            -> ends 796416
#define OFF_TF1B   796416u     // tf1 bf16 1024x384 = 196608 f32 -> ends 993024
#define OFF_QKV    993024u     // qkv bf16 1024x1152 = 589824    -> ends 1582848
#define OFF_AOB    1582848u    // ao bf16 1024x384 = 196608      -> ends 1779456
#define OFF_H1B    1779456u    // h1 bf16 1024x1536 = 786432     -> ends 2565888
#define OFF_WINB   2565888u    // in_w bf16 1152x384 = 221184    -> ends 2787072
#define OFF_WOUTB  2787072u    // out_w bf16 384x384 = 73728     -> ends 2860800
#define OFF_WF1B   2860800u    // ff1_w bf16 1536x384 = 294912   -> ends 3155712
#define OFF_WF2B   3155712u    // ff2_w bf16 1536x384 = 294912   -> ends 3450624

__device__ inline __hip_bfloat16 f2bf(float x) { return __float2bfloat16(x); }
union BFPack { short8 v; __hip_bfloat16 h[8]; };
__device__ inline short8 pack8(float4 a, float4 b)
{
    BFPack p;
    p.h[0] = f2bf(a.x); p.h[1] = f2bf(a.y); p.h[2] = f2bf(a.z); p.h[3] = f2bf(a.w);
    p.h[4] = f2bf(b.x); p.h[5] = f2bf(b.y); p.h[6] = f2bf(b.z); p.h[7] = f2bf(b.w);
    return p.v;
}

// ---------------------------------------------------------------------------
// k_prep: blocks 0..863 weights->bf16 (block 0 zeroes segx+tout+rstat) | 864 setup
__global__ __launch_bounds__(256) void k_prep(
    const float* __restrict__ in_w, const float* __restrict__ out_w,
    const float* __restrict__ ff1_w, const float* __restrict__ ff2_w,
    __hip_bfloat16* __restrict__ winb, __hip_bfloat16* __restrict__ woutb,
    __hip_bfloat16* __restrict__ wf1b, __hip_bfloat16* __restrict__ wf2b,
    const float* __restrict__ sigma,
    const float* __restrict__ fw, const float* __restrict__ fb,
    const float* __restrict__ nsw, const float* __restrict__ nsb,
    float* __restrict__ nsproj_out, float* __restrict__ zero_base)
{
    __shared__ float emb[256];
    __shared__ float noise[256];
    int tid = threadIdx.x;
    int bid = blockIdx.x;

    if (bid == 864) {           // ---- fourier -> noise -> nsproj ----
        float sg = sigma[0];
        if (tid < 128) {
            float fr = expf(-logf(1000.f) * (float)tid / 128.f);
            float x = sg * fr;
            emb[tid]       = cosf(x);
            emb[tid + 128] = sinf(x);
        }
        __syncthreads();
        {
            const float* wr = fw + (size_t)tid * 256;
            float acc = fb[tid];
            for (int i = 0; i < 256; i++) acc += emb[i] * wr[i];
            noise[tid] = acc;
        }
        __syncthreads();
        for (int o = tid; o < 384; o += 256) {
            const float* wr = nsw + (size_t)o * 256;
            float acc = nsb[o];
            for (int i = 0; i < 256; i++) acc += noise[i] * wr[i];
            nsproj_out[o] = acc;
        }
        return;
    }
    if (bid == 0) {             // zero segx+tout+rstat = [0, 9472)
        for (int i = tid; i < 9472; i += 256) zero_base[i] = 0.f;
    }
    size_t e8 = (size_t)bid * 256 + tid;
    const float* src; __hip_bfloat16* dst; size_t off;
    if (e8 < 55296)       { src = in_w;  dst = winb;  off = e8; }
    else if (e8 < 73728)  { src = out_w; dst = woutb; off = e8 - 55296; }
    else if (e8 < 147456) { src = ff1_w; dst = wf1b;  off = e8 - 73728; }
    else                  { src = ff2_w; dst = wf2b;  off = e8 - 147456; }
    float4 a = *(const float4*)(src + off * 8);
    float4 b = *(const float4*)(src + off * 8 + 4);
    *(short8*)(dst + off * 8) = pack8(a, b);
}

// ---------------------------------------------------------------------------
__global__ __launch_bounds__(256) void k_segsum(
    const float* __restrict__ x, const int* __restrict__ idx,
    float* __restrict__ segx)
{
    int a = blockIdx.x * 256 + threadIdx.x;
    if (a < N_ATOM) {
        int t = idx[a];
        atomicAdd(&segx[t * 4 + 0], x[a * 3 + 0]);
        atomicAdd(&segx[t * 4 + 1], x[a * 3 + 1]);
        atomicAdd(&segx[t * 4 + 2], x[a * 3 + 2]);
        atomicAdd(&segx[t * 4 + 3], 1.f);
    }
}

// ---------------------------------------------------------------------------
__device__ inline float blockReduceSum128(float v, volatile float* sm)
{
    #pragma unroll
    for (int off = 32; off > 0; off >>= 1) v += __shfl_down(v, off);
    if ((threadIdx.x & 63) == 0) sm[threadIdx.x >> 6] = v;
    __syncthreads();
    float r = sm[0] + sm[1];
    __syncthreads();
    return r;
}

// token_feat = LN(s)*g+b + nsproj + (cnt>0 ? mean_x@ce_w.T + ce_b : 0)
// (R5-proven; writes f32 residual + bf16 GEMM operand)
__global__ __launch_bounds__(128) void k_tokenfeat(
    const float* __restrict__ s, const float* __restrict__ segx,
    const float* __restrict__ nsproj,
    const float* __restrict__ g, const float* __restrict__ b,
    const float* __restrict__ ce_w, const float* __restrict__ ce_b,
    float* __restrict__ tf, __hip_bfloat16* __restrict__ tfb)
{
    __shared__ float sm[2];
    int t = blockIdx.x, tid = threadIdx.x;
    const float* sr = s + (size_t)t * C_S;
    float x0 = sr[tid], x1 = sr[tid + 128], x2 = sr[tid + 256];
    float total = blockReduceSum128(x0 + x1 + x2, sm);
    float mean = total * (1.f / 384.f);
    float d0 = x0 - mean, d1 = x1 - mean, d2 = x2 - mean;
    float vtot = blockReduceSum128(d0 * d0 + d1 * d1 + d2 * d2, sm);
    float inv = rsqrtf(vtot * (1.f / 384.f) + 1e-5f);
    float cnt = segx[t * 4 + 3];
    float mx0 = 0.f, mx1 = 0.f, mx2 = 0.f;
    int has = cnt > 0.f;
    if (has) {
        float ic = 1.f / cnt;
        mx0 = segx[t * 4 + 0] * ic;
        mx1 = segx[t * 4 + 1] * ic;
        mx2 = segx[t * 4 + 2] * ic;
    }
    float xs[3] = {d0, d1, d2};
    #pragma unroll
    for (int l = 0; l < 3; l++) {
        int c = tid + l * 128;
        float ln = xs[l] * inv * g[c] + b[c];
        float coord = 0.f;
        if (has)
            coord = mx0 * ce_w[c * 3 + 0] + mx1 * ce_w[c * 3 + 1]
                  + mx2 * ce_w[c * 3 + 2] + ce_b[c];
        float v = ln + nsproj[c] + coord;
        tf[(size_t)t * C_S + c] = v;
        tfb[(size_t)t * C_S + c] = f2bf(v);
    }
}

// ---------------------------------------------------------------------------
// plain bf16 MFMA GEMM, bf16 out (qkv): C = A @ W^T + bias
__global__ __launch_bounds__(256) void k_gemm_obf(
    const __hip_bfloat16* __restrict__ A, const __hip_bfloat16* __restrict__ W,
    const float* __restrict__ bias, __hip_bfloat16* __restrict__ C,
    int N, int K)
{
    __shared__ __hip_bfloat16 As[64][72];
    __shared__ __hip_bfloat16 Bs[64][72];

    int tid = threadIdx.x;
    int bm = blockIdx.y * 64, bn = blockIdx.x * 64;
    int w = tid >> 6, lane = tid & 63;
    int wr = (w >> 1) * 32, wc = (w & 1) * 32;
    int fr = lane & 15, kg = lane >> 4;
    int sr = tid >> 2, sc = (tid & 3) << 4;

    f32x4 acc[2][2] = {};
    for (int k0 = 0; k0 < K; k0 += 64) {
        const __hip_bfloat16* ag = A + (size_t)(bm + sr) * K + k0 + sc;
        const __hip_bfloat16* wg = W + (size_t)(bn + sr) * K + k0 + sc;
        short8 a0 = *(const short8*)(ag + 0);
        short8 a1 = *(const short8*)(ag + 8);
        short8 b0 = *(const short8*)(wg + 0);
        short8 b1 = *(const short8*)(wg + 8);
        __syncthreads();
        *(short8*)&As[sr][sc + 0] = a0;
        *(short8*)&As[sr][sc + 8] = a1;
        *(short8*)&Bs[sr][sc + 0] = b0;
        *(short8*)&Bs[sr][sc + 8] = b1;
        __syncthreads();

        short8 af[2][2], bf[2][2];
        #pragma unroll
        for (int i = 0; i < 2; ++i)
            #pragma unroll
            for (int kh = 0; kh < 2; ++kh) {
                af[i][kh] = *(const short8*)&As[wr + i * 16 + fr][kh * 32 + kg * 8];
                bf[i][kh] = *(const short8*)&Bs[wc + i * 16 + fr][kh * 32 + kg * 8];
            }
        #pragma unroll
        for (int kh = 0; kh < 2; ++kh)
            #pragma unroll
            for (int i = 0; i < 2; ++i)
                #pragma unroll
                for (int j = 0; j < 2; ++j)
                    acc[i][j] = __builtin_amdgcn_mfma_f32_16x16x32_bf16(
                        af[i][kh], bf[j][kh], acc[i][j], 0, 0, 0);
    }

    #pragma unroll
    for (int i = 0; i < 2; ++i)
        #pragma unroll
        for (int j = 0; j < 2; ++j) {
            int n = bn + wc + j * 16 + fr;
            float bv = bias[n];
            #pragma unroll
            for (int r = 0; r < 4; ++r) {
                int m = bm + wr + i * 16 + kg * 4 + r;
                C[(size_t)m * N + n] = f2bf(acc[i][j][r] + bv);
            }
        }
}

// ---------------------------------------------------------------------------
// outproj GEMM, f32 out + residual + per-row LN-stats epilogue:
// tf2 = ao @ out_w^T + out_b + tf1; rstat[m] += {sum(tf2_row), sum(tf2_row^2)}
__global__ __launch_bounds__(256) void k_gemm_res_stats(
    const __hip_bfloat16* __restrict__ A, const __hip_bfloat16* __restrict__ W,
    const float* __restrict__ bias, const float* __restrict__ res,
    float* __restrict__ C, float* __restrict__ rstat, int N, int K)
{
    __shared__ __hip_bfloat16 As[64][72];
    __shared__ __hip_bfloat16 Bs[64][72];

    int tid = threadIdx.x;
    int bm = blockIdx.y * 64, bn = blockIdx.x * 64;
    int w = tid >> 6, lane = tid & 63;
    int wr = (w >> 1) * 32, wc = (w & 1) * 32;
    int fr = lane & 15, kg = lane >> 4;
    int sr = tid >> 2, sc = (tid & 3) << 4;

    f32x4 acc[2][2] = {};
    for (int k0 = 0; k0 < K; k0 += 64) {
        const __hip_bfloat16* ag = A + (size_t)(bm + sr) * K + k0 + sc;
        const __hip_bfloat16* wg = W + (size_t)(bn + sr) * K + k0 + sc;
        short8 a0 = *(const short8*)(ag + 0);
        short8 a1 = *(const short8*)(ag + 8);
        short8 b0 = *(const short8*)(wg + 0);
        short8 b1 = *(const short8*)(wg + 8);
        __syncthreads();
        *(short8*)&As[sr][sc + 0] = a0;
        *(short8*)&As[sr][sc + 8] = a1;
        *(short8*)&Bs[sr][sc + 0] = b0;
        *(short8*)&Bs[sr][sc + 8] = b1;
        __syncthreads();

        short8 af[2][2], bf[2][2];
        #pragma unroll
        for (int i = 0; i < 2; ++i)
            #pragma unroll
            for (int kh = 0; kh < 2; ++kh) {
                af[i][kh] = *(const short8*)&As[wr + i * 16 + fr][kh * 32 + kg * 8];
                bf[i][kh] = *(const short8*)&Bs[wc + i * 16 + fr][kh * 32 + kg * 8];
            }
        #pragma unroll
        for (int kh = 0; kh < 2; ++kh)
            #pragma unroll
            for (int i = 0; i < 2; ++i)
                #pragma unroll
                for (int j = 0; j < 2; ++j)
                    acc[i][j] = __builtin_amdgcn_mfma_f32_16x16x32_bf16(
                        af[i][kh], bf[j][kh], acc[i][j], 0, 0, 0);
    }

    float st0[2][4] = {}, st1[2][4] = {};
    #pragma unroll
    for (int i = 0; i < 2; ++i)
        #pragma unroll
        for (int j = 0; j < 2; ++j) {
            int n = bn + wc + j * 16 + fr;
            float bv = bias[n];
            #pragma unroll
            for (int r = 0; r < 4; ++r) {
                int m = bm + wr + i * 16 + kg * 4 + r;
                float v = acc[i][j][r] + bv + res[(size_t)m * N + n];
                C[(size_t)m * N + n] = v;
                st0[i][r] += v;
                st1[i][r] += v * v;
            }
        }
    // reduce across the 16 fr-lanes (same kg), then 2 atomics per row per wave
    #pragma unroll
    for (int off = 1; off < 16; off <<= 1)
        #pragma unroll
        for (int i = 0; i < 2; ++i)
            #pragma unroll
            for (int r = 0; r < 4; ++r) {
                st0[i][r] += __shfl_xor(st0[i][r], off);
                st1[i][r] += __shfl_xor(st1[i][r], off);
            }
    if (fr == 0)
        #pragma unroll
        for (int i = 0; i < 2; ++i)
            #pragma unroll
            for (int r = 0; r < 4; ++r) {
                int m = bm + wr + i * 16 + kg * 4 + r;
                atomicAdd(&rstat[m * 2 + 0], st0[i][r]);
                atomicAdd(&rstat[m * 2 + 1], st1[i][r]);
            }
}

// ---------------------------------------------------------------------------
// ff1 GEMM with LN-on-stage using PRECOMPUTED row stats (no reduction here):
// h1 = silu( (LN(tf2)*g+b) @ ff1_w^T + ff1_b ) -> bf16
__global__ __launch_bounds__(256) void k_lnff1(
    const float* __restrict__ X, const __hip_bfloat16* __restrict__ W,
    const float* __restrict__ bias,
    const float* __restrict__ g, const float* __restrict__ b,
    const float* __restrict__ rstat, __hip_bfloat16* __restrict__ OUT)
{
    __shared__ __hip_bfloat16 As[64][72];
    __shared__ __hip_bfloat16 Bs[64][72];

    int tid = threadIdx.x;
    int bm = blockIdx.y * 64, bn = blockIdx.x * 64;
    int sr = tid >> 2, sc4 = tid & 3;

    const float* xrow = X + (size_t)(bm + sr) * 384;
    float s1 = rstat[(bm + sr) * 2 + 0];
    float s2 = rstat[(bm + sr) * 2 + 1];
    float mean = s1 * (1.f / 384.f);
    float rstd = rsqrtf(s2 * (1.f / 384.f) - mean * mean + 1e-5f);

    int w = tid >> 6, lane = tid & 63;
    int wr = (w >> 1) * 32, wc = (w & 1) * 32;
    int fr = lane & 15, kg = lane >> 4;

    f32x4 acc[2][2] = {};
    for (int k0 = 0; k0 < 384; k0 += 64) {
        int c0 = k0 + sc4 * 16;
        short8 apack[2];
        #pragma unroll
        for (int hh = 0; hh < 2; ++hh) {
            int c = c0 + hh * 8;
            float xv[8], gv[8], bv[8];
            *(float4*)&xv[0] = *(const float4*)(xrow + c);
            *(float4*)&xv[4] = *(const float4*)(xrow + c + 4);
            *(float4*)&gv[0] = *(const float4*)(g + c);
            *(float4*)&gv[4] = *(const float4*)(g + c + 4);
            *(float4*)&bv[0] = *(const float4*)(b + c);
            *(float4*)&bv[4] = *(const float4*)(b + c + 4);
            BFPack p;
            #pragma unroll
            for (int j = 0; j < 8; ++j)
                p.h[j] = f2bf((xv[j] - mean) * rstd * gv[j] + bv[j]);
            apack[hh] = p.v;
        }
        const __hip_bfloat16* wg = W + (size_t)(bn + sr) * 384 + c0;
        short8 bb0 = *(const short8*)(wg + 0);
        short8 bb1 = *(const short8*)(wg + 8);
        __syncthreads();
        *(short8*)&As[sr][sc4 * 16 + 0] = apack[0];
        *(short8*)&As[sr][sc4 * 16 + 8] = apack[1];
        *(short8*)&Bs[sr][sc4 * 16 + 0] = bb0;
        *(short8*)&Bs[sr][sc4 * 16 + 8] = bb1;
        __syncthreads();

        short8 af[2][2], bf[2][2];
        #pragma unroll
        for (int i = 0; i < 2; ++i)
            #pragma unroll
            for (int kh = 0; kh < 2; ++kh) {
                af[i][kh] = *(const short8*)&As[wr + i * 16 + fr][kh * 32 + kg * 8];
                bf[i][kh] = *(const short8*)&Bs[wc + i * 16 + fr][kh * 32 + kg * 8];
            }
        #pragma unroll
        for (int kh = 0; kh < 2; ++kh)
            #pragma unroll
            for (int i = 0; i < 2; ++i)
                #pragma unroll
                for (int j = 0; j < 2; ++j)
                    acc[i][j] = __builtin_amdgcn_mfma_f32_16x16x32_bf16(
                        af[i][kh], bf[j][kh], acc[i][j], 0, 0, 0);
    }

    #pragma unroll
    for (int i = 0; i < 2; ++i)
        #pragma unroll
        for (int j = 0; j < 2; ++j) {
            int n = bn + wc + j * 16 + fr;
            float bsv = bias[n];
            #pragma unroll
            for (int r = 0; r < 4; ++r) {
                int m = bm + wr + i * 16 + kg * 4 + r;
                float v = acc[i][j][r] + bsv;
                v = v / (1.f + __expf(-v));   // silu
                OUT[(size_t)m * 1536 + n] = f2bf(v);
            }
        }
}

// ---------------------------------------------------------------------------
// ff2 GEMM with tout epilogue (R11-validated): tf3 never materialized
__global__ __launch_bounds__(256) void k_gemm_tout(
    const __hip_bfloat16* __restrict__ A, const __hip_bfloat16* __restrict__ W,
    const float* __restrict__ bias, const float* __restrict__ res,
    const float* __restrict__ co_w, float* __restrict__ tout, int K)
{
    __shared__ __hip_bfloat16 As[64][72];
    __shared__ __hip_bfloat16 Bs[64][72];

    int tid = threadIdx.x;
    int bm = blockIdx.y * 64, bn = blockIdx.x * 64;
    int w = tid >> 6, lane = tid & 63;
    int wr = (w >> 1) * 32, wc = (w & 1) * 32;
    int fr = lane & 15, kg = lane >> 4;
    int sr = tid >> 2, sc = (tid & 3) << 4;

    f32x4 acc[2][2] = {};
    for (int k0 = 0; k0 < K; k0 += 64) {
        const __hip_bfloat16* ag = A + (size_t)(bm + sr) * K + k0 + sc;
        const __hip_bfloat16* wg = W + (size_t)(bn + sr) * K + k0 + sc;
        short8 a0 = *(const short8*)(ag + 0);
        short8 a1 = *(const short8*)(ag + 8);
        short8 b0 = *(const short8*)(wg + 0);
        short8 b1 = *(const short8*)(wg + 8);
        __syncthreads();
        *(short8*)&As[sr][sc + 0] = a0;
        *(short8*)&As[sr][sc + 8] = a1;
        *(short8*)&Bs[sr][sc + 0] = b0;
        *(short8*)&Bs[sr][sc + 8] = b1;
        __syncthreads();

        short8 af[2][2], bf[2][2];
        #pragma unroll
        for (int i = 0; i < 2; ++i)
            #pragma unroll
            for (int kh = 0; kh < 2; ++kh) {
                af[i][kh] = *(const short8*)&As[wr + i * 16 + fr][kh * 32 + kg * 8];
                bf[i][kh] = *(const short8*)&Bs[wc + i * 16 + fr][kh * 32 + kg * 8];
            }
        #pragma unroll
        for (int kh = 0; kh < 2; ++kh)
            #pragma unroll
            for (int i = 0; i < 2; ++i)
                #pragma unroll
                for (int j = 0; j < 2; ++j)
                    acc[i][j] = __builtin_amdgcn_mfma_f32_16x16x32_bf16(
                        af[i][kh], bf[j][kh], acc[i][j], 0, 0, 0);
    }

    float part[2][4][3] = {};
    #pragma unroll
    for (int j = 0; j < 2; ++j) {
        int n = bn + wc + j * 16 + fr;
        float bv = bias[n];
        float c0 = co_w[n], c1 = co_w[384 + n], c2 = co_w[768 + n];
        #pragma unroll
        for (int i = 0; i < 2; ++i)
            #pragma unroll
            for (int r = 0; r < 4; ++r) {
                int m = bm + wr + i * 16 + kg * 4 + r;
                float v = acc[i][j][r] + bv + res[(size_t)m * 384 + n];
                part[i][r][0] += v * c0;
                part[i][r][1] += v * c1;
                part[i][r][2] += v * c2;
            }
    }
    #pragma unroll
    for (int off = 1; off < 16; off <<= 1)
        #pragma unroll
        for (int i = 0; i < 2; ++i)
            #pragma unroll
            for (int r = 0; r < 4; ++r)
                #pragma unroll
                for (int jj = 0; jj < 3; ++jj)
                    part[i][r][jj] += __shfl_xor(part[i][r][jj], off);
    if (fr == 0)
        #pragma unroll
        for (int i = 0; i < 2; ++i)
            #pragma unroll
            for (int r = 0; r < 4; ++r) {
                int m = bm + wr + i * 16 + kg * 4 + r;
                #pragma unroll
                for (int jj = 0; jj < 3; ++jj)
                    atomicAdd(&tout[m * 3 + jj], part[i][r][jj]);
            }
}

// ---------------------------------------------------------------------------
// MFMA flash attention (R5-proven): block = (32 Q-rows, head).
#define QB 32
#define TB 64

__global__ __launch_bounds__(256) void k_attn(
    const __hip_bfloat16* __restrict__ qkv, __hip_bfloat16* __restrict__ ao)
{
    __shared__ __hip_bfloat16 Ks[TB][104];
    __shared__ __hip_bfloat16 Vt[96][72];
    __shared__ __hip_bfloat16 Ps[QB][72];
    __shared__ float wmax[QB][4];
    __shared__ float wsum[QB][4];

    int tid = threadIdx.x;
    int w = tid >> 6, l = tid & 63;
    int fr = l & 15, kg = l >> 4;
    int row0 = blockIdx.x * QB;
    int h = blockIdx.y;
    const float scale = 0.1020620726f;   // 1/sqrt(96)

    short8 qf[2][3];
    #pragma unroll
    for (int qs = 0; qs < 2; ++qs)
        #pragma unroll
        for (int dg = 0; dg < 3; ++dg)
            qf[qs][dg] = *(const short8*)(qkv
                + (size_t)(row0 + qs * 16 + fr) * 1152 + h * 96 + dg * 32 + kg * 8);

    float m[2][4], lsum[2][4];
    #pragma unroll
    for (int qs = 0; qs < 2; ++qs)
        #pragma unroll
        for (int r = 0; r < 4; ++r) { m[qs][r] = -1e30f; lsum[qs][r] = 0.f; }

    const int myqs = w >> 1;
    const int d0 = (w & 1) * 48;
    f32x4 acc_o[3] = {};

    int st_t = tid >> 2, st_c = (tid & 3) * 24;
    int vt_t = tid & 63, vt_d = (tid >> 6) * 24;

    for (int tile = 0; tile < N_TOK / TB; ++tile) {
        int t0 = tile * TB;
        __syncthreads();
        {
            const __hip_bfloat16* src =
                qkv + (size_t)(t0 + st_t) * 1152 + 384 + h * 96 + st_c;
            short8 k0 = *(const short8*)(src);
            short8 k1 = *(const short8*)(src + 8);
            short8 k2 = *(const short8*)(src + 16);
            *(short8*)&Ks[st_t][st_c + 0]  = k0;
            *(short8*)&Ks[st_t][st_c + 8]  = k1;
            *(short8*)&Ks[st_t][st_c + 16] = k2;
        }
        {
            const __hip_bfloat16* src =
                qkv + (size_t)(t0 + vt_t) * 1152 + 768 + h * 96 + vt_d;
            BFPack p0, p1, p2;
            p0.v = *(const short8*)(src);
            p1.v = *(const short8*)(src + 8);
            p2.v = *(const short8*)(src + 16);
            #pragma unroll
            for (int j = 0; j < 8; ++j) {
                Vt[vt_d + j][vt_t]      = p0.h[j];
                Vt[vt_d + 8 + j][vt_t]  = p1.h[j];
                Vt[vt_d + 16 + j][vt_t] = p2.h[j];
            }
        }
        __syncthreads();

        f32x4 s[2] = {};
        #pragma unroll
        for (int dg = 0; dg < 3; ++dg) {
            short8 kf = *(const short8*)&Ks[w * 16 + fr][dg * 32 + kg * 8];
            s[0] = __builtin_amdgcn_mfma_f32_16x16x32_bf16(qf[0][dg], kf, s[0], 0, 0, 0);
            s[1] = __builtin_amdgcn_mfma_f32_16x16x32_bf16(qf[1][dg], kf, s[1], 0, 0, 0);
        }

        #pragma unroll
        for (int qs = 0; qs < 2; ++qs) {
            float rmax[4];
            #pragma unroll
            for (int r = 0; r < 4; ++r) rmax[r] = s[qs][r] * scale;
            #pragma unroll
            for (int off = 1; off < 16; off <<= 1)
                #pragma unroll
                for (int r = 0; r < 4; ++r)
                    rmax[r] = fmaxf(rmax[r], __shfl_xor(rmax[r], off));
            if (fr == 0)
                #pragma unroll
                for (int r = 0; r < 4; ++r)
                    wmax[qs * 16 + kg * 4 + r][w] = rmax[r];
        }
        __syncthreads();

        float sc_my[4];
        #pragma unroll
        for (int qs = 0; qs < 2; ++qs) {
            float psum[4];
            #pragma unroll
            for (int r = 0; r < 4; ++r) {
                int row = qs * 16 + kg * 4 + r;
                float4 wm = *(const float4*)&wmax[row][0];
                float gm = fmaxf(fmaxf(wm.x, wm.y), fmaxf(wm.z, wm.w));
                float mnew = fmaxf(m[qs][r], gm);
                float scr = __expf(m[qs][r] - mnew);
                float p = __expf(s[qs][r] * scale - mnew);
                m[qs][r] = mnew;
                lsum[qs][r] *= scr;
                if (qs == myqs) sc_my[r] = scr;
                Ps[row][w * 16 + fr] = f2bf(p);
                psum[r] = p;
            }
            #pragma unroll
            for (int off = 1; off < 16; off <<= 1)
                #pragma unroll
                for (int r = 0; r < 4; ++r)
                    psum[r] += __shfl_xor(psum[r], off);
            if (fr == 0)
                #pragma unroll
                for (int r = 0; r < 4; ++r)
                    wsum[qs * 16 + kg * 4 + r][w] = psum[r];
        }
        __syncthreads();

        #pragma unroll
        for (int qs = 0; qs < 2; ++qs)
            #pragma unroll
            for (int r = 0; r < 4; ++r) {
                float4 wsv = *(const float4*)&wsum[qs * 16 + kg * 4 + r][0];
                lsum[qs][r] += wsv.x + wsv.y + wsv.z + wsv.w;
            }

        #pragma unroll
        for (int ds = 0; ds < 3; ++ds)
            #pragma unroll
            for (int r = 0; r < 4; ++r)
                acc_o[ds][r] *= sc_my[r];
        #pragma unroll
        for (int kk = 0; kk < 2; ++kk) {
            short8 pf = *(const short8*)&Ps[myqs * 16 + fr][kk * 32 + kg * 8];
            #pragma unroll
            for (int ds = 0; ds < 3; ++ds) {
                short8 vf = *(const short8*)&Vt[d0 + ds * 16 + fr][kk * 32 + kg * 8];
                acc_o[ds] = __builtin_amdgcn_mfma_f32_16x16x32_bf16(pf, vf, acc_o[ds], 0, 0, 0);
            }
        }
    }

    #pragma unroll
    for (int r = 0; r < 4; ++r) {
        float inv = 1.f / lsum[myqs][r];
        int q = row0 + myqs * 16 + kg * 4 + r;
        #pragma unroll
        for (int ds = 0; ds < 3; ++ds) {
            int d = h * 96 + d0 + ds * 16 + fr;
            ao[(size_t)q * C_S + d] = f2bf(acc_o[ds][r] * inv);
        }
    }
}

// ---------------------------------------------------------------------------
// gather: out[a] = tout[idx[a]] + co_b   (12 B per atom)
__global__ __launch_bounds__(256) void k_gather(
    const float* __restrict__ tout, const int* __restrict__ idx,
    const float* __restrict__ co_b, float* __restrict__ out)
{
    int a = blockIdx.x * 256 + threadIdx.x;
    if (a < N_ATOM) {
        int t = idx[a];
        out[a * 3 + 0] = tout[t * 3 + 0] + co_b[0];
        out[a * 3 + 1] = tout[t * 3 + 1] + co_b[1];
        out[a * 3 + 2] = tout[t * 3 + 2] + co_b[2];
    }
}

// ---------------------------------------------------------------------------
extern "C" void kernel_launch(void* const* d_in, const int* in_sizes, int n_in,
                              void* d_out, int out_size, void* d_ws, size_t ws_size,
                              hipStream_t stream)
{
    const float* x_noisy   = (const float*)d_in[0];
    const float* s         = (const float*)d_in[1];
    // d_in[2] = z : dead code in the reference (z_cond unused) -> never read
    const float* sigma     = (const float*)d_in[3];
    const int*   a2t       = (const int*)d_in[4];
    const float* fourier_w = (const float*)d_in[5];
    const float* fourier_b = (const float*)d_in[6];
    const float* ns_w      = (const float*)d_in[7];
    const float* ns_b      = (const float*)d_in[8];
    const float* lns_g     = (const float*)d_in[11];
    const float* lns_b     = (const float*)d_in[12];
    const float* ce_w      = (const float*)d_in[15];
    const float* ce_b      = (const float*)d_in[16];
    const float* in_w      = (const float*)d_in[17];
    const float* in_b      = (const float*)d_in[18];
    const float* out_w     = (const float*)d_in[19];
    const float* out_b     = (const float*)d_in[20];
    const float* ffln_g    = (const float*)d_in[21];
    const float* ffln_b    = (const float*)d_in[22];
    const float* ff1_w     = (const float*)d_in[23];
    const float* ff1_b     = (const float*)d_in[24];
    const float* ff2_w     = (const float*)d_in[25];
    const float* ff2_b     = (const float*)d_in[26];
    const float* co_w      = (const float*)d_in[27];
    const float* co_b      = (const float*)d_in[28];

    float* ws  = (float*)d_ws;
    float* out = (float*)d_out;
    __hip_bfloat16* tf1b  = (__hip_bfloat16*)(ws + OFF_TF1B);
    __hip_bfloat16* qkvb  = (__hip_bfloat16*)(ws + OFF_QKV);
    __hip_bfloat16* aob   = (__hip_bfloat16*)(ws + OFF_AOB);
    __hip_bfloat16* h1b   = (__hip_bfloat16*)(ws + OFF_H1B);
    __hip_bfloat16* winb  = (__hip_bfloat16*)(ws + OFF_WINB);
    __hip_bfloat16* woutb = (__hip_bfloat16*)(ws + OFF_WOUTB);
    __hip_bfloat16* wf1b  = (__hip_bfloat16*)(ws + OFF_WF1B);
    __hip_bfloat16* wf2b  = (__hip_bfloat16*)(ws + OFF_WF2B);

    // 1. prep: weights->bf16 | setup | zero segx/tout/rstat (block 0)
    hipLaunchKernelGGL(k_prep, dim3(865), dim3(256), 0, stream,
                       in_w, out_w, ff1_w, ff2_w, winb, woutb, wf1b, wf2b,
                       sigma, fourier_w, fourier_b, ns_w, ns_b,
                       ws + OFF_NSPROJ, ws);
    // 2. segment sums
    hipLaunchKernelGGL(k_segsum, dim3(96), dim3(256), 0, stream,
                       x_noisy, a2t, ws + OFF_SEGX);
    // 3. tokenfeat -> tf1 f32 + tf1b bf16
    hipLaunchKernelGGL(k_tokenfeat, dim3(N_TOK), dim3(128), 0, stream,
                       s, ws + OFF_SEGX, ws + OFF_NSPROJ, lns_g, lns_b,
                       ce_w, ce_b, ws + OFF_TF1, tf1b);
    // 4. qkv = tf1 @ in_w^T + in_b -> bf16
    hipLaunchKernelGGL(k_gemm_obf, dim3(18, 16), dim3(256), 0, stream,
                       tf1b, winb, in_b, qkvb, 1152, 384);
    // 5. MFMA flash attention
    hipLaunchKernelGGL(k_attn, dim3(N_TOK / QB, NH), dim3(256), 0, stream,
                       qkvb, aob);
    // 6. tf2 = tf1 + ao @ out_w^T + out_b  (f32) + LN row-stats epilogue
    hipLaunchKernelGGL(k_gemm_res_stats, dim3(6, 16), dim3(256), 0, stream,
                       aob, woutb, out_b, ws + OFF_TF1, ws + OFF_TF2,
                       ws + OFF_RSTAT, 384, 384);
    // 7. h1 = silu(LN(tf2) @ ff1_w^T + ff1_b) -> bf16 (stats precomputed)
    hipLaunchKernelGGL(k_lnff1, dim3(24, 16), dim3(256), 0, stream,
                       ws + OFF_TF2, wf1b, ff1_b, ffln_g, ffln_b,
                       ws + OFF_RSTAT, h1b);
    // 8. ff2 GEMM + tout epilogue (tf3 never materialized)
    hipLaunchKernelGGL(k_gemm_tout, dim3(6, 16), dim3(256), 0, stream,
                       h1b, wf2b, ff2_b, ws + OFF_TF2, co_w,
                       ws + OFF_TOUT, 1536);
    // 9. gather
    hipLaunchKernelGGL(k_gather, dim3(96), dim3(256), 0, stream,
                       ws + OFF_TOUT, a2t, co_b, out);
}